// Round 2
// baseline (8876.403 us; speedup 1.0000x reference)
//
#include <hip/hip_runtime.h>
#include <stdint.h>

#define NN 64
#define TT 512
#define DD 512
#define HH 512
#define H3 1536
#define MROWS (NN * TT)   // 32768

typedef _Float16 f16;

__device__ __forceinline__ unsigned short f2bf(float f) {
    unsigned int u = __float_as_uint(f);
    return (unsigned short)((u + 0x7fffu + ((u >> 16) & 1u)) >> 16);
}
__device__ __forceinline__ float lo16(unsigned int u) { return __uint_as_float(u << 16); }
__device__ __forceinline__ float hi16(unsigned int u) { return __uint_as_float(u & 0xffff0000u); }

__device__ __forceinline__ float loadx(const float* p) { return *p; }
__device__ __forceinline__ float loadx(const f16* p) { return (float)(*p); }
__device__ __forceinline__ void storex(float* p, float v) { *p = v; }
__device__ __forceinline__ void storex(f16* p, float v) { *p = (f16)v; }

// ---------------------------------------------------------------------------
// Kernel 1: repack W [512][1536] fp32 -> bf16 swizzled [dir][64 k8][1536 col][8 j]
// so the scan's per-thread 8-k gate chunk is one lane-coalesced dwordx4.
// grid (48 col-tiles, 8 k-tiles, 2 dirs), block 256.
// ---------------------------------------------------------------------------
__global__ void repack_w(const float* __restrict__ srcF,
                         const float* __restrict__ srcB,
                         unsigned short* __restrict__ dst) {
    __shared__ unsigned short tile[64][33];
    const int dir = blockIdx.z;
    const float* src = dir ? srcB : srcF;
    const int c0 = blockIdx.x * 32;   // column (output unit), 0..1535
    const int k0 = blockIdx.y * 64;   // row (k), 0..511
    const int t = threadIdx.x;
    const int lx = t & 31;
    const int ly = t >> 5;            // 0..7
    #pragma unroll
    for (int i = 0; i < 8; ++i) {
        tile[ly + i * 8][lx] = f2bf(src[(size_t)(k0 + ly + i * 8) * H3 + c0 + lx]);
    }
    __syncthreads();
    const int cl = t & 31;
    const int k8l = t >> 5;           // 0..7
    unsigned short v[8] __attribute__((aligned(16)));
    #pragma unroll
    for (int j = 0; j < 8; ++j) v[j] = tile[k8l * 8 + j][cl];
    const size_t base = (((size_t)dir * 64 + (k0 >> 3) + k8l) * H3 + c0 + cl) * 8;
    *(uint4*)(dst + base) = *(const uint4*)v;
}

// ---------------------------------------------------------------------------
// Kernel 2: xm[dir][row][c] = x[row][:] @ W_x_dir[:, c]   (fp32 inputs/acc)
// 128x128 tile, BK=32, 256 threads, 8x8 micro-tile per thread.
// grid (12 col-blocks, 256 row-blocks, 2 dirs).
// ---------------------------------------------------------------------------
template <typename XT>
__global__ __launch_bounds__(256, 2) void gemm_xw(const float* __restrict__ x,
                                                  const float* __restrict__ wxf,
                                                  const float* __restrict__ wxb,
                                                  XT* __restrict__ xm) {
    const int dir = blockIdx.z;
    const float* w = dir ? wxb : wxf;
    XT* out = xm + (size_t)dir * MROWS * H3;
    const int c0 = blockIdx.x * 128;
    const int r0 = blockIdx.y * 128;
    __shared__ float sA[32][128];   // [k][m]
    __shared__ float sB[32][128];   // [k][n]
    const int t = threadIdx.x;
    const int tx = t & 15, ty = t >> 4;
    float acc[8][8];
    #pragma unroll
    for (int i = 0; i < 8; ++i)
        #pragma unroll
        for (int j = 0; j < 8; ++j) acc[i][j] = 0.f;

    for (int k0 = 0; k0 < DD; k0 += 32) {
        // stage A: 128 rows x 32 k, transposed into sA[k][m]
        #pragma unroll
        for (int i = 0; i < 4; ++i) {
            int idx = t * 4 + i;            // 0..1023
            int m = idx >> 3;               // 0..127
            int c = idx & 7;                // 0..7 (k chunk of 4)
            float4 u = *(const float4*)(x + (size_t)(r0 + m) * DD + k0 + c * 4);
            sA[c * 4 + 0][m] = u.x;
            sA[c * 4 + 1][m] = u.y;
            sA[c * 4 + 2][m] = u.z;
            sA[c * 4 + 3][m] = u.w;
        }
        // stage B: 32 k x 128 cols
        #pragma unroll
        for (int i = 0; i < 4; ++i) {
            int idx = t * 4 + i;            // 0..1023
            int kk = idx >> 5;              // 0..31
            int ch = idx & 31;              // 0..31 (col chunk of 4)
            *(float4*)&sB[kk][ch * 4] =
                *(const float4*)(w + (size_t)(k0 + kk) * H3 + c0 + ch * 4);
        }
        __syncthreads();
        for (int k = 0; k < 32; ++k) {
            float4 a0 = *(const float4*)&sA[k][ty * 8];
            float4 a1 = *(const float4*)&sA[k][ty * 8 + 4];
            float4 b0 = *(const float4*)&sB[k][tx * 8];
            float4 b1 = *(const float4*)&sB[k][tx * 8 + 4];
            float a[8] = {a0.x, a0.y, a0.z, a0.w, a1.x, a1.y, a1.z, a1.w};
            float b[8] = {b0.x, b0.y, b0.z, b0.w, b1.x, b1.y, b1.z, b1.w};
            #pragma unroll
            for (int ii = 0; ii < 8; ++ii)
                #pragma unroll
                for (int jj = 0; jj < 8; ++jj)
                    acc[ii][jj] = fmaf(a[ii], b[jj], acc[ii][jj]);
        }
        __syncthreads();
    }
    #pragma unroll
    for (int ii = 0; ii < 8; ++ii) {
        size_t r = (size_t)(r0 + ty * 8 + ii);
        #pragma unroll
        for (int jj = 0; jj < 8; ++jj)
            storex(&out[r * H3 + c0 + tx * 8 + jj], acc[ii][jj]);
    }
}

// ---------------------------------------------------------------------------
// Kernel 3: GRU scan. One block per (n, dir); 512 threads = 512 hidden units.
// h state fp32 in LDS; weights bf16 swizzled (whT); xm precomputed.
// grid (64, 2), block 512.
// ---------------------------------------------------------------------------
#define FMA8(acc, u, h0, h1)                         \
    acc = fmaf(lo16((u).x), (h0).x, acc);            \
    acc = fmaf(hi16((u).x), (h0).y, acc);            \
    acc = fmaf(lo16((u).y), (h0).z, acc);            \
    acc = fmaf(hi16((u).y), (h0).w, acc);            \
    acc = fmaf(lo16((u).z), (h1).x, acc);            \
    acc = fmaf(hi16((u).z), (h1).y, acc);            \
    acc = fmaf(lo16((u).w), (h1).z, acc);            \
    acc = fmaf(hi16((u).w), (h1).w, acc);

template <typename XT>
__global__ __launch_bounds__(512) void gru_scan(const XT* __restrict__ xm,
                                                const unsigned short* __restrict__ whT,
                                                const float* __restrict__ b_f,
                                                const float* __restrict__ b_b,
                                                float* __restrict__ out) {
    const int n = blockIdx.x;
    const int dir = blockIdx.y;
    const int tid = threadIdx.x;
    const float* bias = dir ? b_b : b_f;
    const float bz = bias[tid];
    const float br = bias[512 + tid];
    const float bg = bias[1024 + tid];
    const uint4* w4 = (const uint4*)whT + (size_t)dir * 64 * H3;
    const uint4* wz4 = w4 + tid;
    const uint4* wr4 = w4 + 512 + tid;
    const uint4* wg4 = w4 + 1024 + tid;
    const XT* xbase = xm + ((size_t)dir * MROWS + (size_t)n * TT) * H3;

    __shared__ __align__(16) float sh[512];
    sh[tid] = 0.f;
    float hprev = 0.f;
    __syncthreads();

    for (int s = 0; s < TT; ++s) {
        const int tc = dir ? (TT - 1 - s) : s;
        const XT* xrow = xbase + (size_t)tc * H3;
        float az = 0.f, ar = 0.f, ag = 0.f;
        #pragma unroll 4
        for (int k8 = 0; k8 < 64; ++k8) {
            const uint4 uz = wz4[k8 * H3];
            const uint4 ur = wr4[k8 * H3];
            const uint4 ug = wg4[k8 * H3];
            const float4 h0 = *(const float4*)(sh + k8 * 8);
            const float4 h1 = *(const float4*)(sh + k8 * 8 + 4);
            FMA8(az, uz, h0, h1);
            FMA8(ar, ur, h0, h1);
            FMA8(ag, ug, h0, h1);
        }
        const float xz = loadx(xrow + tid);
        const float xr = loadx(xrow + 512 + tid);
        const float xg = loadx(xrow + 1024 + tid);
        const float z = 1.f / (1.f + __expf(-(xz + az + bz)));
        const float r = 1.f / (1.f + __expf(-(xr + ar + br)));
        const float g = 1.f - 2.f / (1.f + __expf(2.f * (xg + r * ag + bg)));
        const float hnew = (1.f - z) * g + z * hprev;
        __syncthreads();                 // all dot-reads of sh done
        sh[tid] = hnew;
        hprev = hnew;
        out[((size_t)n * TT + tc) * 1024 + (size_t)dir * 512 + tid] = hnew;
        __syncthreads();                 // h visible before next step's reads
    }
}

// ---------------------------------------------------------------------------
// Emergency fallback (any ws_size, uses NO workspace): fused scan that also
// computes the x-projection per step from raw fp32 W_x / W_h. Slow but safe.
// grid (64, 2), block 512.
// ---------------------------------------------------------------------------
__global__ __launch_bounds__(512) void gru_scan_fused(const float* __restrict__ x,
                                                      const float* __restrict__ wxf,
                                                      const float* __restrict__ whf,
                                                      const float* __restrict__ b_f,
                                                      const float* __restrict__ wxb,
                                                      const float* __restrict__ whb,
                                                      const float* __restrict__ b_b,
                                                      float* __restrict__ out) {
    const int n = blockIdx.x;
    const int dir = blockIdx.y;
    const int tid = threadIdx.x;
    const float* wx = dir ? wxb : wxf;
    const float* wh = dir ? whb : whf;
    const float* bias = dir ? b_b : b_f;
    const float bz = bias[tid];
    const float br = bias[512 + tid];
    const float bg = bias[1024 + tid];

    __shared__ float sh[512];
    __shared__ float shx[512];
    sh[tid] = 0.f;
    float hprev = 0.f;
    __syncthreads();

    for (int s = 0; s < TT; ++s) {
        const int tc = dir ? (TT - 1 - s) : s;
        shx[tid] = x[((size_t)n * TT + tc) * DD + tid];
        __syncthreads();                 // shx ready
        float az = 0.f, ar = 0.f, ag = 0.f;
        float xz = 0.f, xr = 0.f, xg = 0.f;
        #pragma unroll 2
        for (int k = 0; k < DD; ++k) {
            const float hk = sh[k];
            const float xk = shx[k];
            const size_t rowb = (size_t)k * H3 + tid;
            az = fmaf(wh[rowb], hk, az);
            ar = fmaf(wh[rowb + 512], hk, ar);
            ag = fmaf(wh[rowb + 1024], hk, ag);
            xz = fmaf(wx[rowb], xk, xz);
            xr = fmaf(wx[rowb + 512], xk, xr);
            xg = fmaf(wx[rowb + 1024], xk, xg);
        }
        const float z = 1.f / (1.f + __expf(-(xz + az + bz)));
        const float r = 1.f / (1.f + __expf(-(xr + ar + br)));
        const float g = 1.f - 2.f / (1.f + __expf(2.f * (xg + r * ag + bg)));
        const float hnew = (1.f - z) * g + z * hprev;
        __syncthreads();                 // dot-reads done
        sh[tid] = hnew;
        hprev = hnew;
        out[((size_t)n * TT + tc) * 1024 + (size_t)dir * 512 + tid] = hnew;
        __syncthreads();                 // sh visible for next step
    }
}

// ---------------------------------------------------------------------------
extern "C" void kernel_launch(void* const* d_in, const int* in_sizes, int n_in,
                              void* d_out, int out_size, void* d_ws, size_t ws_size,
                              hipStream_t stream) {
    const float* x   = (const float*)d_in[0];
    const float* wxf = (const float*)d_in[1];
    const float* whf = (const float*)d_in[2];
    const float* bf_ = (const float*)d_in[3];
    const float* wxb = (const float*)d_in[4];
    const float* whb = (const float*)d_in[5];
    const float* bb_ = (const float*)d_in[6];
    float* out = (float*)d_out;

    const size_t whT_bytes    = (size_t)2 * HH * H3 * sizeof(unsigned short); // 3.1 MB
    const size_t xm_f32_bytes = (size_t)2 * MROWS * H3 * sizeof(float);       // 402.7 MB
    const size_t xm_f16_bytes = (size_t)2 * MROWS * H3 * sizeof(f16);         // 201.3 MB

    if (ws_size >= xm_f32_bytes + whT_bytes) {
        float* xm = (float*)d_ws;
        unsigned short* whT = (unsigned short*)((char*)d_ws + xm_f32_bytes);
        repack_w<<<dim3(48, 8, 2), 256, 0, stream>>>(whf, whb, whT);
        gemm_xw<float><<<dim3(12, 256, 2), 256, 0, stream>>>(x, wxf, wxb, xm);
        gru_scan<float><<<dim3(64, 2), 512, 0, stream>>>(xm, whT, bf_, bb_, out);
    } else if (ws_size >= xm_f16_bytes + whT_bytes) {
        f16* xm = (f16*)d_ws;
        unsigned short* whT = (unsigned short*)((char*)d_ws + xm_f16_bytes);
        repack_w<<<dim3(48, 8, 2), 256, 0, stream>>>(whf, whb, whT);
        gemm_xw<f16><<<dim3(12, 256, 2), 256, 0, stream>>>(x, wxf, wxb, xm);
        gru_scan<f16><<<dim3(64, 2), 512, 0, stream>>>(xm, whT, bf_, bb_, out);
    } else {
        // No usable workspace: fused, zero-scratch, correct-but-slow path.
        gru_scan_fused<<<dim3(64, 2), 512, 0, stream>>>(x, wxf, whf, bf_,
                                                        wxb, whb, bb_, out);
    }
}

// Round 3
// 8139.587 us; speedup vs baseline: 1.0905x; 1.0905x over previous
//
#include <hip/hip_runtime.h>
#include <stdint.h>

#define NN 64
#define TT 512
#define DD 512
#define HH 512
#define H3 1536
#define MROWS (NN * TT)   // 32768

typedef _Float16 f16;
typedef f16 f16x8 __attribute__((ext_vector_type(8)));
typedef float f32x4 __attribute__((ext_vector_type(4)));

// ws layout (bytes):
//   xm    f16 [2][512][64][1536]                     201,326,592
//   wpack f16 [2][64][2 nt][16 ks][64 lane][8 j]       4,194,304
//   hbuf  f16 [2 buf][2 dir][64 seq][512 unit]           262,144
//   cnt   u32 [2] (256B apart)                               512
#define XM_BYTES   ((size_t)2 * TT * NN * H3 * 2)
#define WPACK_BYTES ((size_t)2 * 64 * 2 * 16 * 64 * 8 * 2)
#define HBUF_BYTES ((size_t)2 * 2 * NN * HH * 2)
#define CNT_BYTES  ((size_t)512)

// ---------------------------------------------------------------------------
// Kernel 1: repack W_h fp32 -> f16 MFMA-B-fragment order.
// For (dir, blk): dst[((nt*16+ks)*64+lane)*8 + j] = W[k][col]
//   k = ks*32 + (lane>>4)*8 + j ; col = gate_base + blk*8 + (local)
// grid (64, 2), block 256.
// ---------------------------------------------------------------------------
__global__ void repack_wh_frag(const float* __restrict__ whf,
                               const float* __restrict__ whb,
                               f16* __restrict__ wpack) {
    const int blk = blockIdx.x;
    const int dir = blockIdx.y;
    const float* src = dir ? whb : whf;
    f16* dst = wpack + ((size_t)(dir * 64 + blk)) * 16384;
    const int j0 = blk * 8;
    for (int c = threadIdx.x; c < 2048; c += blockDim.x) {
        const int lane = c & 63;
        const int nloc = ((c >> 10) << 4) + (lane & 15);   // 0..31 local col
        const int kq = ((c >> 6) & 15) * 32 + (lane >> 4) * 8;
        int gcol = 0;
        bool valid = true;
        if (nloc < 8)       gcol = j0 + nloc;
        else if (nloc < 16) gcol = 512 + j0 + (nloc - 8);
        else if (nloc < 24) gcol = 1024 + j0 + (nloc - 16);
        else valid = false;
        f16x8 v;
        #pragma unroll
        for (int j = 0; j < 8; ++j)
            v[j] = valid ? (f16)src[(size_t)(kq + j) * H3 + gcol] : (f16)0.f;
        *(f16x8*)(dst + (size_t)c * 8) = v;
    }
}

// ---------------------------------------------------------------------------
// Kernel 2: xm[dir][t][n][c] = x[n][t][:] @ W_x_dir[:, c]  (fp32 acc, f16 out)
// 128x128 tile, BK=32, 256 threads, 8x8 micro-tile.
// grid (12, 256, 2).
// ---------------------------------------------------------------------------
__global__ __launch_bounds__(256, 2) void gemm_xw(const float* __restrict__ x,
                                                  const float* __restrict__ wxf,
                                                  const float* __restrict__ wxb,
                                                  f16* __restrict__ xm) {
    const int dir = blockIdx.z;
    const float* w = dir ? wxb : wxf;
    f16* out = xm + (size_t)dir * MROWS * H3;
    const int c0 = blockIdx.x * 128;
    const int r0 = blockIdx.y * 128;
    __shared__ float sA[32][128];
    __shared__ float sB[32][128];
    const int t = threadIdx.x;
    const int tx = t & 15, ty = t >> 4;
    float acc[8][8];
    #pragma unroll
    for (int i = 0; i < 8; ++i)
        #pragma unroll
        for (int j = 0; j < 8; ++j) acc[i][j] = 0.f;

    for (int k0 = 0; k0 < DD; k0 += 32) {
        #pragma unroll
        for (int i = 0; i < 4; ++i) {
            int idx = t * 4 + i;
            int m = idx >> 3;
            int c = idx & 7;
            float4 u = *(const float4*)(x + (size_t)(r0 + m) * DD + k0 + c * 4);
            sA[c * 4 + 0][m] = u.x;
            sA[c * 4 + 1][m] = u.y;
            sA[c * 4 + 2][m] = u.z;
            sA[c * 4 + 3][m] = u.w;
        }
        #pragma unroll
        for (int i = 0; i < 4; ++i) {
            int idx = t * 4 + i;
            int kk = idx >> 5;
            int ch = idx & 31;
            *(float4*)&sB[kk][ch * 4] =
                *(const float4*)(w + (size_t)(k0 + kk) * H3 + c0 + ch * 4);
        }
        __syncthreads();
        for (int k = 0; k < 32; ++k) {
            float4 a0 = *(const float4*)&sA[k][ty * 8];
            float4 a1 = *(const float4*)&sA[k][ty * 8 + 4];
            float4 b0 = *(const float4*)&sB[k][tx * 8];
            float4 b1 = *(const float4*)&sB[k][tx * 8 + 4];
            float a[8] = {a0.x, a0.y, a0.z, a0.w, a1.x, a1.y, a1.z, a1.w};
            float b[8] = {b0.x, b0.y, b0.z, b0.w, b1.x, b1.y, b1.z, b1.w};
            #pragma unroll
            for (int ii = 0; ii < 8; ++ii)
                #pragma unroll
                for (int jj = 0; jj < 8; ++jj)
                    acc[ii][jj] = fmaf(a[ii], b[jj], acc[ii][jj]);
        }
        __syncthreads();
    }
    #pragma unroll
    for (int ii = 0; ii < 8; ++ii) {
        const size_t r = (size_t)(r0 + ty * 8 + ii);
        const size_t tt = r & 511, n = r >> 9;     // row = n*512 + t
        f16x8 v;
        #pragma unroll
        for (int jj = 0; jj < 8; ++jj) v[jj] = (f16)acc[ii][jj];
        *(f16x8*)(out + (tt * 64 + n) * H3 + c0 + tx * 8) = v;
    }
}

// ---------------------------------------------------------------------------
// Kernel 3: MFMA column-split GRU scan with device-scope step barrier.
// grid (64 unit-slices, 2 dirs), block 512 (8 waves).
// Wave w: mt = w>>1 (seq tile), nt = w&1 (col tile). B-frags in registers.
// Epilogue: thread = seq*8 + u owns (seq, unit j0+u); hprev in register.
// ---------------------------------------------------------------------------
__global__ __launch_bounds__(512, 1) void gru_scan_mfma(
        const f16* __restrict__ xm,
        const f16* __restrict__ wpack,
        const float* __restrict__ b_f, const float* __restrict__ b_b,
        f16* __restrict__ hbuf,
        unsigned int* __restrict__ cnt,
        float* __restrict__ out) {
    const int blk = blockIdx.x;
    const int dir = blockIdx.y;
    const int tid = threadIdx.x;
    const int lane = tid & 63, wave = tid >> 6;
    const int mt = wave >> 1, nt = wave & 1;
    const int j0 = blk * 8;

    // B-fragments: loaded once, live in VGPRs for all 512 steps.
    f16x8 bfrag[16];
    {
        const f16* wp = wpack + (((size_t)(dir * 64 + blk) * 2 + nt)) * 8192;
        #pragma unroll
        for (int ks = 0; ks < 16; ++ks)
            bfrag[ks] = *(const f16x8*)(wp + ((size_t)(ks * 64 + lane)) * 8);
    }

    const int eseq = tid >> 3, eu = tid & 7;
    const float* bias = dir ? b_b : b_f;
    const float bz = bias[j0 + eu];
    const float br = bias[512 + j0 + eu];
    const float bg = bias[1024 + j0 + eu];
    const f16* xmd = xm + (size_t)dir * TT * NN * H3;
    f16* hb = hbuf + dir * (NN * HH);            // [buf][dir][seq][unit]
    unsigned int* cdir = cnt + dir * 64;         // 256 B apart

    __shared__ float pre[64][25];                // [seq][24 cols + pad]

    const int aseq = mt * 16 + (lane & 15);
    const int kb = (lane >> 4) * 8;
    const int pr0 = mt * 16 + ((lane >> 4) << 2);
    const int pc = nt * 16 + (lane & 15);

    float hprev = 0.f;
    int tc = dir ? (TT - 1) : 0;
    size_t xo = ((size_t)tc * 64 + eseq) * H3 + j0 + eu;
    float pxz = (float)xmd[xo];
    float pxr = (float)xmd[xo + 512];
    float pxg = (float)xmd[xo + 1024];

    for (int s = 0; s < TT; ++s) {
        const f16* hr = hb + (s & 1) * (2 * NN * HH) + aseq * HH + kb;
        f32x4 acc = {0.f, 0.f, 0.f, 0.f};
        #pragma unroll
        for (int ks = 0; ks < 16; ++ks) {
            f16x8 af = *(const f16x8*)(hr + ks * 32);
            acc = __builtin_amdgcn_mfma_f32_16x16x32_f16(af, bfrag[ks], acc, 0, 0, 0);
        }
        if (pc < 24) {
            #pragma unroll
            for (int r = 0; r < 4; ++r) pre[pr0 + r][pc] = acc[r];
        }
        __syncthreads();

        const float z = 1.f / (1.f + __expf(-(pxz + pre[eseq][eu] + bz)));
        const float r = 1.f / (1.f + __expf(-(pxr + pre[eseq][8 + eu] + br)));
        const float g = 1.f - 2.f / (1.f + __expf(2.f * (pxg + r * pre[eseq][16 + eu] + bg)));
        const float hnew = (1.f - z) * g + z * hprev;
        hprev = hnew;
        out[((size_t)eseq * TT + tc) * 1024 + dir * 512 + j0 + eu] = hnew;
        hb[((s + 1) & 1) * (2 * NN * HH) + eseq * HH + j0 + eu] = (f16)hnew;

        if (s < TT - 1) {
            const int tcn = dir ? (TT - 2 - s) : (s + 1);
            const size_t xo2 = ((size_t)tcn * 64 + eseq) * H3 + j0 + eu;
            pxz = (float)xmd[xo2];
            pxr = (float)xmd[xo2 + 512];
            pxg = (float)xmd[xo2 + 1024];
            tc = tcn;
            __syncthreads();                 // drains vmcnt: h stores now in L2
            if (tid == 0) {
                __threadfence();             // release: write back to coherence point
                atomicAdd(cdir, 1u);
                const unsigned tgt = 64u * (unsigned)(s + 1);
                while (__hip_atomic_load(cdir, __ATOMIC_RELAXED,
                                         __HIP_MEMORY_SCOPE_AGENT) < tgt)
                    __builtin_amdgcn_s_sleep(1);
                __threadfence();             // acquire: invalidate L1/L2
            }
            __syncthreads();
        }
    }
}

// ---------------------------------------------------------------------------
// Zero-workspace fallback (correct but slow).
// ---------------------------------------------------------------------------
__global__ __launch_bounds__(512) void gru_scan_fused(const float* __restrict__ x,
                                                      const float* __restrict__ wxf,
                                                      const float* __restrict__ whf,
                                                      const float* __restrict__ b_f,
                                                      const float* __restrict__ wxb,
                                                      const float* __restrict__ whb,
                                                      const float* __restrict__ b_b,
                                                      float* __restrict__ out) {
    const int n = blockIdx.x;
    const int dir = blockIdx.y;
    const int tid = threadIdx.x;
    const float* wx = dir ? wxb : wxf;
    const float* wh = dir ? whb : whf;
    const float* bias = dir ? b_b : b_f;
    const float bz = bias[tid];
    const float br = bias[512 + tid];
    const float bg = bias[1024 + tid];

    __shared__ float sh[512];
    __shared__ float shx[512];
    sh[tid] = 0.f;
    float hprev = 0.f;
    __syncthreads();

    for (int s = 0; s < TT; ++s) {
        const int tc = dir ? (TT - 1 - s) : s;
        shx[tid] = x[((size_t)n * TT + tc) * DD + tid];
        __syncthreads();
        float az = 0.f, ar = 0.f, ag = 0.f;
        float xz = 0.f, xr = 0.f, xg = 0.f;
        #pragma unroll 2
        for (int k = 0; k < DD; ++k) {
            const float hk = sh[k];
            const float xk = shx[k];
            const size_t rowb = (size_t)k * H3 + tid;
            az = fmaf(wh[rowb], hk, az);
            ar = fmaf(wh[rowb + 512], hk, ar);
            ag = fmaf(wh[rowb + 1024], hk, ag);
            xz = fmaf(wx[rowb], xk, xz);
            xr = fmaf(wx[rowb + 512], xk, xr);
            xg = fmaf(wx[rowb + 1024], xk, xg);
        }
        const float z = 1.f / (1.f + __expf(-(xz + az + bz)));
        const float r = 1.f / (1.f + __expf(-(xr + ar + br)));
        const float g = 1.f - 2.f / (1.f + __expf(2.f * (xg + r * ag + bg)));
        const float hnew = (1.f - z) * g + z * hprev;
        __syncthreads();
        sh[tid] = hnew;
        hprev = hnew;
        out[((size_t)n * TT + tc) * 1024 + (size_t)dir * 512 + tid] = hnew;
        __syncthreads();
    }
}

// ---------------------------------------------------------------------------
extern "C" void kernel_launch(void* const* d_in, const int* in_sizes, int n_in,
                              void* d_out, int out_size, void* d_ws, size_t ws_size,
                              hipStream_t stream) {
    const float* x   = (const float*)d_in[0];
    const float* wxf = (const float*)d_in[1];
    const float* whf = (const float*)d_in[2];
    const float* bf_ = (const float*)d_in[3];
    const float* wxb = (const float*)d_in[4];
    const float* whb = (const float*)d_in[5];
    const float* bb_ = (const float*)d_in[6];
    float* out = (float*)d_out;

    const size_t need = XM_BYTES + WPACK_BYTES + HBUF_BYTES + CNT_BYTES; // ~206 MB

    if (ws_size >= need) {
        f16* xm = (f16*)d_ws;
        f16* wpack = (f16*)((char*)d_ws + XM_BYTES);
        f16* hbuf = (f16*)((char*)d_ws + XM_BYTES + WPACK_BYTES);
        unsigned int* cnt = (unsigned int*)((char*)d_ws + XM_BYTES + WPACK_BYTES + HBUF_BYTES);
        // zero h state (h0 = 0) and the step-barrier counters
        hipMemsetAsync(hbuf, 0, HBUF_BYTES + CNT_BYTES, stream);
        repack_wh_frag<<<dim3(64, 2), 256, 0, stream>>>(whf, whb, wpack);
        gemm_xw<<<dim3(12, 256, 2), 256, 0, stream>>>(x, wxf, wxb, xm);
        gru_scan_mfma<<<dim3(64, 2), 512, 0, stream>>>(xm, wpack, bf_, bb_,
                                                       hbuf, cnt, out);
    } else {
        gru_scan_fused<<<dim3(64, 2), 512, 0, stream>>>(x, wxf, whf, bf_,
                                                        wxb, whb, bb_, out);
    }
}

// Round 4
// 7385.464 us; speedup vs baseline: 1.2019x; 1.1021x over previous
//
#include <hip/hip_runtime.h>
#include <stdint.h>

#define NN 64
#define TT 512
#define DD 512
#define HH 512
#define H3 1536
#define MROWS (NN * TT)   // 32768

typedef _Float16 f16;
typedef f16 f16x8 __attribute__((ext_vector_type(8)));
typedef float f32x4 __attribute__((ext_vector_type(4)));
typedef unsigned long long ull;

// ws layout (bytes):
//   xm    f16 [2][512][64][1536]                     201,326,592
//   wpack f16 [2][64][2 nt][16 ks][64 lane][8 j]       4,194,304
//   hbuf  f16 [2 buf][2 dir][64 seq][512 unit]           262,144
//   flags u32 [2 dir][64 blk]                                512
#define XM_BYTES    ((size_t)2 * TT * NN * H3 * 2)
#define WPACK_BYTES ((size_t)2 * 64 * 2 * 16 * 64 * 8 * 2)
#define HBUF_BYTES  ((size_t)2 * 2 * NN * HH * 2)
#define CNT_BYTES   ((size_t)512)

// ---------------------------------------------------------------------------
// Kernel 1: repack W_h fp32 -> f16 MFMA-B-fragment order. grid (64,2), 256 thr.
// ---------------------------------------------------------------------------
__global__ void repack_wh_frag(const float* __restrict__ whf,
                               const float* __restrict__ whb,
                               f16* __restrict__ wpack) {
    const int blk = blockIdx.x;
    const int dir = blockIdx.y;
    const float* src = dir ? whb : whf;
    f16* dst = wpack + ((size_t)(dir * 64 + blk)) * 16384;
    const int j0 = blk * 8;
    for (int c = threadIdx.x; c < 2048; c += blockDim.x) {
        const int lane = c & 63;
        const int nloc = ((c >> 10) << 4) + (lane & 15);   // 0..31 local col
        const int kq = ((c >> 6) & 15) * 32 + (lane >> 4) * 8;
        int gcol = 0;
        bool valid = true;
        if (nloc < 8)       gcol = j0 + nloc;
        else if (nloc < 16) gcol = 512 + j0 + (nloc - 8);
        else if (nloc < 24) gcol = 1024 + j0 + (nloc - 16);
        else valid = false;
        f16x8 v;
        #pragma unroll
        for (int j = 0; j < 8; ++j)
            v[j] = valid ? (f16)src[(size_t)(kq + j) * H3 + gcol] : (f16)0.f;
        *(f16x8*)(dst + (size_t)c * 8) = v;
    }
}

// ---------------------------------------------------------------------------
// Kernel 2: xm[dir][t][n][c] = x[n][t][:] @ W_x_dir[:, c]  (fp32 acc, f16 out)
// 128x128 tile, BK=32, 256 threads, 8x8 micro-tile. grid (12, 256, 2).
// ---------------------------------------------------------------------------
__global__ __launch_bounds__(256, 2) void gemm_xw(const float* __restrict__ x,
                                                  const float* __restrict__ wxf,
                                                  const float* __restrict__ wxb,
                                                  f16* __restrict__ xm) {
    const int dir = blockIdx.z;
    const float* w = dir ? wxb : wxf;
    f16* out = xm + (size_t)dir * MROWS * H3;
    const int c0 = blockIdx.x * 128;
    const int r0 = blockIdx.y * 128;
    __shared__ float sA[32][128];
    __shared__ float sB[32][128];
    const int t = threadIdx.x;
    const int tx = t & 15, ty = t >> 4;
    float acc[8][8];
    #pragma unroll
    for (int i = 0; i < 8; ++i)
        #pragma unroll
        for (int j = 0; j < 8; ++j) acc[i][j] = 0.f;

    for (int k0 = 0; k0 < DD; k0 += 32) {
        #pragma unroll
        for (int i = 0; i < 4; ++i) {
            int idx = t * 4 + i;
            int m = idx >> 3;
            int c = idx & 7;
            float4 u = *(const float4*)(x + (size_t)(r0 + m) * DD + k0 + c * 4);
            sA[c * 4 + 0][m] = u.x;
            sA[c * 4 + 1][m] = u.y;
            sA[c * 4 + 2][m] = u.z;
            sA[c * 4 + 3][m] = u.w;
        }
        #pragma unroll
        for (int i = 0; i < 4; ++i) {
            int idx = t * 4 + i;
            int kk = idx >> 5;
            int ch = idx & 31;
            *(float4*)&sB[kk][ch * 4] =
                *(const float4*)(w + (size_t)(k0 + kk) * H3 + c0 + ch * 4);
        }
        __syncthreads();
        for (int k = 0; k < 32; ++k) {
            float4 a0 = *(const float4*)&sA[k][ty * 8];
            float4 a1 = *(const float4*)&sA[k][ty * 8 + 4];
            float4 b0 = *(const float4*)&sB[k][tx * 8];
            float4 b1 = *(const float4*)&sB[k][tx * 8 + 4];
            float a[8] = {a0.x, a0.y, a0.z, a0.w, a1.x, a1.y, a1.z, a1.w};
            float b[8] = {b0.x, b0.y, b0.z, b0.w, b1.x, b1.y, b1.z, b1.w};
            #pragma unroll
            for (int ii = 0; ii < 8; ++ii)
                #pragma unroll
                for (int jj = 0; jj < 8; ++jj)
                    acc[ii][jj] = fmaf(a[ii], b[jj], acc[ii][jj]);
        }
        __syncthreads();
    }
    #pragma unroll
    for (int ii = 0; ii < 8; ++ii) {
        const size_t r = (size_t)(r0 + ty * 8 + ii);
        const size_t tt = r & 511, n = r >> 9;     // row = n*512 + t
        f16x8 v;
        #pragma unroll
        for (int jj = 0; jj < 8; ++jj) v[jj] = (f16)acc[ii][jj];
        *(f16x8*)(out + (tt * 64 + n) * H3 + c0 + tx * 8) = v;
    }
}

// ---------------------------------------------------------------------------
// Kernel 3: MFMA column-split GRU scan, fence-free device-coherent exchange.
// All cross-block data moves via sc1 (relaxed agent atomics) -> Infinity Cache;
// no buffer_wbl2 / buffer_inv, so xm stays L2-cached.
// grid (64, 2), block 512 (8 waves: 4 mt x 2 nt).
// ---------------------------------------------------------------------------
__global__ __launch_bounds__(512, 1) void gru_scan_mfma(
        const f16* __restrict__ xm,
        const f16* __restrict__ wpack,
        const float* __restrict__ b_f, const float* __restrict__ b_b,
        f16* __restrict__ hbuf,
        unsigned int* __restrict__ flags,
        float* __restrict__ out) {
    const int blk = blockIdx.x;
    const int dir = blockIdx.y;
    const int tid = threadIdx.x;
    const int lane = tid & 63, wave = tid >> 6;
    const int mt = wave >> 1, nt = wave & 1;
    const int j0 = blk * 8;

    // B-fragments: loaded once, resident for all 512 steps.
    f16x8 bfrag[16];
    {
        const f16* wp = wpack + (((size_t)(dir * 64 + blk) * 2 + nt)) * 8192;
        #pragma unroll
        for (int ks = 0; ks < 16; ++ks)
            bfrag[ks] = *(const f16x8*)(wp + ((size_t)(ks * 64 + lane)) * 8);
    }

    const int eseq = tid >> 3, eu = tid & 7;
    const float* bias = dir ? b_b : b_f;
    const float bz = bias[j0 + eu];
    const float br = bias[512 + j0 + eu];
    const float bg = bias[1024 + j0 + eu];
    const f16* xmd = xm + (size_t)dir * TT * NN * H3;
    f16* hb = hbuf + dir * (NN * HH);            // [buf][dir][seq][unit]
    unsigned int* fdir = flags + dir * 64;

    __shared__ float pre[64][25];                // [seq][24 cols + pad]

    const int aseq = mt * 16 + (lane & 15);
    const int kb = (lane >> 4) * 8;
    const int pr0 = mt * 16 + ((lane >> 4) << 2);
    const int pc = nt * 16 + (lane & 15);

    float hprev = 0.f;
    int tc = dir ? (TT - 1) : 0;
    size_t xo = ((size_t)tc * 64 + eseq) * H3 + j0 + eu;
    float pxz = (float)xmd[xo];
    float pxr = (float)xmd[xo + 512];
    float pxg = (float)xmd[xo + 1024];

    union Frag { ull q[2]; f16x8 v; };
    union H16 { f16 h; unsigned short u; };

    for (int s = 0; s < TT; ++s) {
        // ---- recurrent matmul: A = h(s) read device-coherent from IC ----
        const f16* hr = hb + (s & 1) * (2 * NN * HH) + aseq * HH + kb;
        Frag fr[16];
        #pragma unroll
        for (int ks = 0; ks < 16; ++ks) {
            const ull* p = (const ull*)(hr + ks * 32);
            fr[ks].q[0] = __hip_atomic_load(p,     __ATOMIC_RELAXED, __HIP_MEMORY_SCOPE_AGENT);
            fr[ks].q[1] = __hip_atomic_load(p + 1, __ATOMIC_RELAXED, __HIP_MEMORY_SCOPE_AGENT);
        }
        f32x4 acc = {0.f, 0.f, 0.f, 0.f};
        #pragma unroll
        for (int ks = 0; ks < 16; ++ks)
            acc = __builtin_amdgcn_mfma_f32_16x16x32_f16(fr[ks].v, bfrag[ks], acc, 0, 0, 0);
        if (pc < 24) {
            #pragma unroll
            for (int r = 0; r < 4; ++r) pre[pr0 + r][pc] = acc[r];
        }
        __syncthreads();

        // ---- gate math (thread owns (eseq, j0+eu)) ----
        const float z = 1.f / (1.f + __expf(-(pxz + pre[eseq][eu] + bz)));
        const float r = 1.f / (1.f + __expf(-(pxr + pre[eseq][8 + eu] + br)));
        const float g = 1.f - 2.f / (1.f + __expf(2.f * (pxg + r * pre[eseq][16 + eu] + bg)));
        const float hnew = (1.f - z) * g + z * hprev;
        hprev = hnew;
        out[((size_t)eseq * TT + tc) * 1024 + dir * 512 + j0 + eu] = hnew;

        // ---- publish h(s+1): packed u32 sc1 stores (even eu lanes) ----
        H16 hx; hx.h = (f16)hnew;
        const unsigned int ob = (unsigned int)__shfl_xor((int)hx.u, 1, 64);
        if (!(eu & 1)) {
            unsigned int pk = (unsigned int)hx.u | (ob << 16);
            f16* hw = hb + ((s + 1) & 1) * (2 * NN * HH) + eseq * HH + j0 + eu;
            __hip_atomic_store((unsigned int*)hw, pk,
                               __ATOMIC_RELAXED, __HIP_MEMORY_SCOPE_AGENT);
        }

        if (s < TT - 1) {
            // prefetch next x-projection (plain cached loads, overlap the wait)
            const int tcn = dir ? (TT - 2 - s) : (s + 1);
            const size_t xo2 = ((size_t)tcn * 64 + eseq) * H3 + j0 + eu;
            pxz = (float)xmd[xo2];
            pxr = (float)xmd[xo2 + 512];
            pxg = (float)xmd[xo2 + 1024];
            tc = tcn;
            __syncthreads();   // drains vmcnt: this block's h stores reached IC
            if (wave == 0) {
                if (lane == 0)
                    __hip_atomic_store(&fdir[blk], (unsigned int)(s + 1),
                                       __ATOMIC_RELAXED, __HIP_MEMORY_SCOPE_AGENT);
                const unsigned int tgt = (unsigned int)(s + 1);
                while (true) {
                    unsigned int v = __hip_atomic_load(&fdir[lane],
                                __ATOMIC_RELAXED, __HIP_MEMORY_SCOPE_AGENT);
                    if (__all(v >= tgt)) break;
                    __builtin_amdgcn_s_sleep(2);
                }
            }
            __syncthreads();   // all waves held until every block published h
        }
    }
}

// ---------------------------------------------------------------------------
// Zero-workspace fallback (correct but slow).
// ---------------------------------------------------------------------------
__global__ __launch_bounds__(512) void gru_scan_fused(const float* __restrict__ x,
                                                      const float* __restrict__ wxf,
                                                      const float* __restrict__ whf,
                                                      const float* __restrict__ b_f,
                                                      const float* __restrict__ wxb,
                                                      const float* __restrict__ whb,
                                                      const float* __restrict__ b_b,
                                                      float* __restrict__ out) {
    const int n = blockIdx.x;
    const int dir = blockIdx.y;
    const int tid = threadIdx.x;
    const float* wx = dir ? wxb : wxf;
    const float* wh = dir ? whb : whf;
    const float* bias = dir ? b_b : b_f;
    const float bz = bias[tid];
    const float br = bias[512 + tid];
    const float bg = bias[1024 + tid];

    __shared__ float sh[512];
    __shared__ float shx[512];
    sh[tid] = 0.f;
    float hprev = 0.f;
    __syncthreads();

    for (int s = 0; s < TT; ++s) {
        const int tc = dir ? (TT - 1 - s) : s;
        shx[tid] = x[((size_t)n * TT + tc) * DD + tid];
        __syncthreads();
        float az = 0.f, ar = 0.f, ag = 0.f;
        float xz = 0.f, xr = 0.f, xg = 0.f;
        #pragma unroll 2
        for (int k = 0; k < DD; ++k) {
            const float hk = sh[k];
            const float xk = shx[k];
            const size_t rowb = (size_t)k * H3 + tid;
            az = fmaf(wh[rowb], hk, az);
            ar = fmaf(wh[rowb + 512], hk, ar);
            ag = fmaf(wh[rowb + 1024], hk, ag);
            xz = fmaf(wx[rowb], xk, xz);
            xr = fmaf(wx[rowb + 512], xk, xr);
            xg = fmaf(wx[rowb + 1024], xk, xg);
        }
        const float z = 1.f / (1.f + __expf(-(xz + az + bz)));
        const float r = 1.f / (1.f + __expf(-(xr + ar + br)));
        const float g = 1.f - 2.f / (1.f + __expf(2.f * (xg + r * ag + bg)));
        const float hnew = (1.f - z) * g + z * hprev;
        __syncthreads();
        sh[tid] = hnew;
        hprev = hnew;
        out[((size_t)n * TT + tc) * 1024 + (size_t)dir * 512 + tid] = hnew;
        __syncthreads();
    }
}

// ---------------------------------------------------------------------------
extern "C" void kernel_launch(void* const* d_in, const int* in_sizes, int n_in,
                              void* d_out, int out_size, void* d_ws, size_t ws_size,
                              hipStream_t stream) {
    const float* x   = (const float*)d_in[0];
    const float* wxf = (const float*)d_in[1];
    const float* whf = (const float*)d_in[2];
    const float* bf_ = (const float*)d_in[3];
    const float* wxb = (const float*)d_in[4];
    const float* whb = (const float*)d_in[5];
    const float* bb_ = (const float*)d_in[6];
    float* out = (float*)d_out;

    const size_t need = XM_BYTES + WPACK_BYTES + HBUF_BYTES + CNT_BYTES; // ~206 MB

    if (ws_size >= need) {
        f16* xm = (f16*)d_ws;
        f16* wpack = (f16*)((char*)d_ws + XM_BYTES);
        f16* hbuf = (f16*)((char*)d_ws + XM_BYTES + WPACK_BYTES);
        unsigned int* flags = (unsigned int*)((char*)d_ws + XM_BYTES + WPACK_BYTES + HBUF_BYTES);
        // zero h state (h0 = 0) and the per-block step flags
        hipMemsetAsync(hbuf, 0, HBUF_BYTES + CNT_BYTES, stream);
        repack_wh_frag<<<dim3(64, 2), 256, 0, stream>>>(whf, whb, wpack);
        gemm_xw<<<dim3(12, 256, 2), 256, 0, stream>>>(x, wxf, wxb, xm);
        gru_scan_mfma<<<dim3(64, 2), 512, 0, stream>>>(xm, wpack, bf_, bb_,
                                                       hbuf, flags, out);
    } else {
        gru_scan_fused<<<dim3(64, 2), 512, 0, stream>>>(x, wxf, whf, bf_,
                                                        wxb, whb, bb_, out);
    }
}